// Round 1
// baseline (1736.658 us; speedup 1.0000x reference)
//
#include <hip/hip_runtime.h>
#include <cstdio>
#include <cmath>

#define NB 4
#define CC 256
#define HW 4096
#define NQ 4   // loop-dim split per sweep (partials combined later)

static constexpr float kEPS = 1e-8f;
static constexpr float kSIG = 0.1f + 1e-8f;

// workspace layout in floats
enum {
  OFF_MEAN = 0,                      // 256
  OFF_INVT = 256,                    // NB*HW
  OFF_INVI = OFF_INVT + NB*HW,       // NB*HW
  OFF_BETA = OFF_INVI + NB*HW,       // NB*HW
  OFF_AG   = OFF_BETA + NB*HW,       // NB*HW  (alpha, later overwritten with gamma)
  OFF_CMAX = OFF_AG   + NB*HW,       // NQ*NB*HW partials
  OFF_WSUM = OFF_CMAX + NQ*NB*HW,    // NQ*NB*HW partials
  OFF_MAXV = OFF_WSUM + NQ*NB*HW,    // NQ*NB*HW partials
  WS_FLOATS = OFF_MAXV + NQ*NB*HW
};

__device__ __forceinline__ float blkReduceSum(float v) {
  __shared__ float sh[4];
  const int lane = threadIdx.x & 63, w = threadIdx.x >> 6;
  #pragma unroll
  for (int o = 32; o > 0; o >>= 1) v += __shfl_down(v, o, 64);
  __syncthreads();
  if (lane == 0) sh[w] = v;
  __syncthreads();
  return sh[0] + sh[1] + sh[2] + sh[3];
}

// K1: per-channel mean of featureT over (n, h, w). grid=256 (one block per channel)
__global__ __launch_bounds__(256) void k_mean(const float* __restrict__ fT,
                                              float* __restrict__ ws) {
  const int c = blockIdx.x, t = threadIdx.x;
  float s = 0.f;
  for (int n = 0; n < NB; ++n) {
    const float* p = fT + (size_t)(n*CC + c)*HW;
    #pragma unroll
    for (int k = 0; k < 16; ++k) s += p[k*256 + t];
  }
  const float tot = blkReduceSum(s);
  if (t == 0) ws[OFF_MEAN + c] = tot * (1.0f/16384.0f);
}

// K2: per-pixel inverse channel-norms (1/(||x-mean||+eps)) for T and I.
// grid = NB*HW/64 = 256 blocks; block handles 64 pixels; 4 waves split channels.
__global__ __launch_bounds__(256) void k_norms(const float* __restrict__ fT,
                                               const float* __restrict__ fI,
                                               float* __restrict__ ws) {
  __shared__ float sT[4][64], sI[4][64];
  const int t = threadIdx.x, q = t & 63, a = t >> 6;
  const int n = blockIdx.x >> 6;
  const int q0 = (blockIdx.x & 63) * 64;
  const float* mean = ws + OFF_MEAN;
  float accT = 0.f, accI = 0.f;
  for (int i = 0; i < 64; ++i) {
    const int c = a*64 + i;
    const float m = mean[c];
    const size_t base = (size_t)(n*CC + c)*HW + q0 + q;
    const float vT = fT[base] - m; accT += vT*vT;
    const float vI = fI[base] - m; accI += vI*vI;
  }
  sT[a][q] = accT; sI[a][q] = accI;
  __syncthreads();
  if (t < 64) {
    const float ssT = sT[0][t] + sT[1][t] + sT[2][t] + sT[3][t];
    const float ssI = sI[0][t] + sI[1][t] + sI[2][t] + sI[3][t];
    ws[OFF_INVT + n*HW + q0 + t] = 1.0f/(sqrtf(ssT) + kEPS);
    ws[OFF_INVI + n*HW + q0 + t] = 1.0f/(sqrtf(ssI) + kEPS);
  }
}

// The GEMM sweep. Block owns a 64-wide resident strip (cols of s it reduces
// INTO) and one NQ-th of the loop dimension (dim reduced OVER).
//   mode 0: resident=I(q), loop=T(p), val=s,                   reduce=max  -> colmax partial
//   mode 1: resident=I(q), loop=T(p), val=exp(a_q + b_q*s),    reduce=sum  -> Wsum partial
//   mode 2: resident=T(p), loop=I(q), val=g_q + b_q*s,         reduce=max  -> maxv partial
// grid = NB * 64strips * NQ = 1024 blocks of 256 threads.
__global__ __launch_bounds__(256, 4) void k_sweep(const float* __restrict__ fT,
                                                  const float* __restrict__ fI,
                                                  float* __restrict__ ws,
                                                  const int mode) {
  __shared__ float At[64][64];   // loop-dim chunk  [cc][loopcol]
  __shared__ float Bt[64][64];   // resident chunk  [cc][rescol]
  float (*red)[64] = At;         // reduction buffer aliases At (safe: sync-fenced)

  const int t    = threadIdx.x;
  const int tx   = t & 15, ty = t >> 4;       // 16x16 thread grid, 4x4 acc each
  const int lane = t & 63, wv = t >> 6;       // staging decomposition
  const int b    = blockIdx.x;
  const int h    = b & (NQ - 1);
  const int sid  = b >> 2;                    // log2(NQ)=2
  const int n    = sid >> 6;
  const int col0 = (sid & 63) * 64;
  const int loop0 = h * (HW / NQ);
  const int ntiles = (HW / NQ) / 64;

  const float* __restrict__ mean = ws + OFF_MEAN;
  const float* resP  = (mode == 2) ? fT : fI;
  const float* loopP = (mode == 2) ? fI : fT;
  const float* invR  = (mode == 2) ? ws + OFF_INVT : ws + OFF_INVI;
  const float* invL  = (mode == 2) ? ws + OFF_INVI : ws + OFF_INVT;

  const float invRv = invR[n*HW + col0 + lane];

  float aj[4], bj[4];                         // mode-1 resident-column params
  if (mode == 1) {
    #pragma unroll
    for (int j = 0; j < 4; ++j) {
      aj[j] = ws[OFF_AG   + n*HW + col0 + tx*4 + j];
      bj[j] = ws[OFF_BETA + n*HW + col0 + tx*4 + j];
    }
  }

  float runv = (mode == 1) ? 0.0f : -3.0e38f;

  for (int tile = 0; tile < ntiles; ++tile) {
    const int tile0 = loop0 + tile*64;
    const float invLv = invL[n*HW + tile0 + lane];
    float acc[4][4] = {{0.f}};

    for (int cb = 0; cb < 4; ++cb) {
      __syncthreads();  // protects At/Bt (prev FMA reads / red use) before restage
      #pragma unroll
      for (int k = 0; k < 16; ++k) {
        const int cc = 4*k + wv;
        const int c  = cb*64 + cc;
        const float m = mean[c];
        const size_t rowbase = (size_t)(n*CC + c) * HW;
        At[cc][lane] = (loopP[rowbase + tile0 + lane] - m) * invLv;
        Bt[cc][lane] = (resP [rowbase + col0 + lane] - m) * invRv;
      }
      __syncthreads();
      #pragma unroll
      for (int cc = 0; cc < 64; ++cc) {
        const float4 lv = *(const float4*)&At[cc][ty*4];
        const float4 rv = *(const float4*)&Bt[cc][tx*4];
        const float la[4] = {lv.x, lv.y, lv.z, lv.w};
        const float ra[4] = {rv.x, rv.y, rv.z, rv.w};
        #pragma unroll
        for (int i = 0; i < 4; ++i)
          #pragma unroll
          for (int j = 0; j < 4; ++j)
            acc[i][j] = fmaf(la[i], ra[j], acc[i][j]);
      }
    }
    __syncthreads();  // all FMA reads of At done before red(=At) writes

    float v[4];
    if (mode == 0) {
      #pragma unroll
      for (int j = 0; j < 4; ++j)
        v[j] = fmaxf(fmaxf(acc[0][j], acc[1][j]), fmaxf(acc[2][j], acc[3][j]));
    } else if (mode == 1) {
      #pragma unroll
      for (int j = 0; j < 4; ++j) {
        float s = 0.f;
        #pragma unroll
        for (int i = 0; i < 4; ++i) s += __expf(fmaf(bj[j], acc[i][j], aj[j]));
        v[j] = s;
      }
    } else {
      float gl[4], bl[4];                     // loop-column (q) params
      #pragma unroll
      for (int i = 0; i < 4; ++i) {
        gl[i] = ws[OFF_AG   + n*HW + tile0 + ty*4 + i];
        bl[i] = ws[OFF_BETA + n*HW + tile0 + ty*4 + i];
      }
      #pragma unroll
      for (int j = 0; j < 4; ++j) {
        const float m0 = fmaf(bl[0], acc[0][j], gl[0]);
        const float m1 = fmaf(bl[1], acc[1][j], gl[1]);
        const float m2 = fmaf(bl[2], acc[2][j], gl[2]);
        const float m3 = fmaf(bl[3], acc[3][j], gl[3]);
        v[j] = fmaxf(fmaxf(m0, m1), fmaxf(m2, m3));
      }
    }

    #pragma unroll
    for (int j = 0; j < 4; ++j) red[ty][tx*4 + j] = v[j];
    __syncthreads();
    if (t < 64) {
      if (mode == 1) {
        float s = 0.f;
        #pragma unroll
        for (int k = 0; k < 16; ++k) s += red[k][t];
        runv += s;
      } else {
        #pragma unroll
        for (int k = 0; k < 16; ++k) runv = fmaxf(runv, red[k][t]);
      }
    }
    // next tile's first __syncthreads protects red before At restage
  }

  if (t < 64) {
    const int base = (mode == 0) ? OFF_CMAX : ((mode == 1) ? OFF_WSUM : OFF_MAXV);
    ws[base + h*(NB*HW) + n*HW + col0 + t] = runv;
  }
}

// K4: combine colmax partials -> alpha,beta per (n,q). grid = NB*HW/256 = 64
__global__ __launch_bounds__(256) void k_params(float* __restrict__ ws) {
  const int idx = blockIdx.x*256 + threadIdx.x;
  float cm = ws[OFF_CMAX + idx];
  #pragma unroll
  for (int h = 1; h < NQ; ++h) cm = fmaxf(cm, ws[OFF_CMAX + h*(NB*HW) + idx]);
  const float div   = 0.5f*(1.0f - cm);
  const float inv2d = 1.0f/(2.0f*(div + kEPS));
  ws[OFF_BETA + idx] = inv2d / kSIG;
  ws[OFF_AG   + idx] = (1.0f - inv2d) / kSIG;
}

// K6: gamma = alpha - log(Wsum + eps). grid = 64
__global__ __launch_bounds__(256) void k_gamma(float* __restrict__ ws) {
  const int idx = blockIdx.x*256 + threadIdx.x;
  float s = 0.f;
  #pragma unroll
  for (int h = 0; h < NQ; ++h) s += ws[OFF_WSUM + h*(NB*HW) + idx];
  ws[OFF_AG + idx] = ws[OFF_AG + idx] - logf(s + kEPS);
}

// K8: loss = mean_n -log( mean_p exp(maxv[n,p]) + eps ). single block.
__global__ __launch_bounds__(256) void k_final(const float* __restrict__ ws,
                                               float* __restrict__ out) {
  const int t = threadIdx.x;
  float loss = 0.f;
  for (int n = 0; n < NB; ++n) {
    float s = 0.f;
    for (int k = 0; k < 16; ++k) {
      const int idx = n*HW + k*256 + t;
      float mv = ws[OFF_MAXV + idx];
      #pragma unroll
      for (int h = 1; h < NQ; ++h) mv = fmaxf(mv, ws[OFF_MAXV + h*(NB*HW) + idx]);
      s += __expf(mv);
    }
    const float tot = blkReduceSum(s);
    loss += -logf(tot*(1.0f/4096.0f) + kEPS);
  }
  if (t == 0) out[0] = loss*0.25f;
}

extern "C" void kernel_launch(void* const* d_in, const int* in_sizes, int n_in,
                              void* d_out, int out_size, void* d_ws, size_t ws_size,
                              hipStream_t stream) {
  const float* fT = (const float*)d_in[0];
  const float* fI = (const float*)d_in[1];
  float* out = (float*)d_out;
  float* ws  = (float*)d_ws;

  const size_t need = (size_t)WS_FLOATS * sizeof(float);
  fprintf(stderr, "[CXLoss] ws_size=%zu need=%zu in0=%d in1=%d\n",
          ws_size, need, in_sizes[0], in_sizes[1]);
  if (ws_size < need) {
    fprintf(stderr, "[CXLoss] workspace too small — aborting launch\n");
    return;
  }

  k_mean  <<<256,  256, 0, stream>>>(fT, ws);
  k_norms <<<256,  256, 0, stream>>>(fT, fI, ws);
  k_sweep <<<1024, 256, 0, stream>>>(fT, fI, ws, 0);   // colmax partials
  k_params<<<64,   256, 0, stream>>>(ws);              // alpha, beta
  k_sweep <<<1024, 256, 0, stream>>>(fT, fI, ws, 1);   // Wsum partials
  k_gamma <<<64,   256, 0, stream>>>(ws);              // gamma
  k_sweep <<<1024, 256, 0, stream>>>(fT, fI, ws, 2);   // maxv partials
  k_final <<<1,    256, 0, stream>>>(ws, out);
}

// Round 5
// 250.919 us; speedup vs baseline: 6.9212x; 6.9212x over previous
//
#include <hip/hip_runtime.h>
#include <cmath>

#define NB 4
#define CC 256
#define HW 4096
#define NQ 4   // loop-dim split per sweep (partials combined later)

static constexpr float kEPS = 1e-8f;
static constexpr float kSIG = 0.1f + 1e-8f;

typedef __attribute__((ext_vector_type(8)))  short short8;
typedef __attribute__((ext_vector_type(16))) float f32x16;

// workspace layout in floats
enum {
  OFF_MEAN = 0,                      // 256
  OFF_INVT = 256,                    // NB*HW
  OFF_INVI = OFF_INVT + NB*HW,       // NB*HW
  OFF_BETA = OFF_INVI + NB*HW,       // NB*HW
  OFF_AG   = OFF_BETA + NB*HW,       // NB*HW  (alpha, later overwritten with gamma)
  OFF_CMAX = OFF_AG   + NB*HW,       // NQ*NB*HW partials
  OFF_WSUM = OFF_CMAX + NQ*NB*HW,    // NQ*NB*HW partials
  OFF_MAXV = OFF_WSUM + NQ*NB*HW,    // NQ*NB*HW partials
  OFF_END_SMALL = OFF_MAXV + NQ*NB*HW,
  OFF_GT = OFF_END_SMALL,            // NB*HW*CC ushorts = NB*HW*CC/2 floats
  OFF_GI = OFF_GT + NB*HW*CC/2,
  WS_FLOATS_FULL = OFF_GI + NB*HW*CC/2
};

__device__ __forceinline__ float blkReduceSum(float v) {
  __shared__ float sh[4];
  const int lane = threadIdx.x & 63, w = threadIdx.x >> 6;
  #pragma unroll
  for (int o = 32; o > 0; o >>= 1) v += __shfl_down(v, o, 64);
  __syncthreads();
  if (lane == 0) sh[w] = v;
  __syncthreads();
  return sh[0] + sh[1] + sh[2] + sh[3];
}

__device__ __forceinline__ ushort f2bf(float x) {
  unsigned u = __float_as_uint(x);
  unsigned r = (u + 0x7fffu + ((u >> 16) & 1u)) >> 16;  // RNE
  return (ushort)r;
}

// K1: per-channel mean of featureT over (n, h, w). grid=256
__global__ __launch_bounds__(256) void k_mean(const float* __restrict__ fT,
                                              float* __restrict__ ws) {
  const int c = blockIdx.x, t = threadIdx.x;
  float s = 0.f;
  for (int n = 0; n < NB; ++n) {
    const float* p = fT + (size_t)(n*CC + c)*HW;
    #pragma unroll
    for (int k = 0; k < 16; ++k) s += p[k*256 + t];
  }
  const float tot = blkReduceSum(s);
  if (t == 0) ws[OFF_MEAN + c] = tot * (1.0f/16384.0f);
}

// K2: per-pixel inverse channel-norms for T and I. grid=256
__global__ __launch_bounds__(256) void k_norms(const float* __restrict__ fT,
                                               const float* __restrict__ fI,
                                               float* __restrict__ ws) {
  __shared__ float sT[4][64], sI[4][64];
  const int t = threadIdx.x, q = t & 63, a = t >> 6;
  const int n = blockIdx.x >> 6;
  const int q0 = (blockIdx.x & 63) * 64;
  const float* mean = ws + OFF_MEAN;
  float accT = 0.f, accI = 0.f;
  for (int i = 0; i < 64; ++i) {
    const int c = a*64 + i;
    const float m = mean[c];
    const size_t base = (size_t)(n*CC + c)*HW + q0 + q;
    const float vT = fT[base] - m; accT += vT*vT;
    const float vI = fI[base] - m; accI += vI*vI;
  }
  sT[a][q] = accT; sI[a][q] = accI;
  __syncthreads();
  if (t < 64) {
    const float ssT = sT[0][t] + sT[1][t] + sT[2][t] + sT[3][t];
    const float ssI = sI[0][t] + sI[1][t] + sI[2][t] + sI[3][t];
    ws[OFF_INVT + n*HW + q0 + t] = 1.0f/(sqrtf(ssT) + kEPS);
    ws[OFF_INVI + n*HW + q0 + t] = 1.0f/(sqrtf(ssI) + kEPS);
  }
}

// K3: normalize + transpose to bf16 [n][p][c]. grid = 2*NB*64*4 = 2048
__global__ __launch_bounds__(256) void k_prep(const float* __restrict__ fT,
                                              const float* __restrict__ fI,
                                              float* __restrict__ ws) {
  __shared__ float lds[64][65];      // [p][c]
  const int t = threadIdx.x;
  int bid = blockIdx.x;
  const int tensor = (bid >= 1024); bid &= 1023;
  const int n  = bid >> 8;
  const int pt = (bid & 255) >> 2;
  const int ct = bid & 3;
  const int p0 = pt * 64, c0 = ct * 64;

  const float* __restrict__ src = tensor ? fI : fT;
  const float* __restrict__ inv = ws + (tensor ? OFF_INVI : OFF_INVT);
  ushort* __restrict__ dst = (ushort*)(ws + (tensor ? OFF_GI : OFF_GT));

  const int pcol = t & 63, crb = t >> 6;
  const float invv = inv[n*HW + p0 + pcol];
  #pragma unroll
  for (int i = 0; i < 16; ++i) {
    const int cr = crb + 4*i;
    const float m = ws[OFF_MEAN + c0 + cr];
    const float v = src[((size_t)(n*CC + c0 + cr))*HW + p0 + pcol];
    lds[pcol][cr] = (v - m) * invv;
  }
  __syncthreads();
  const int cpi = t & 31, prb = t >> 5;
  #pragma unroll
  for (int j = 0; j < 8; ++j) {
    const int p = prb + 8*j;
    ushort2 u;
    u.x = f2bf(lds[p][2*cpi]);
    u.y = f2bf(lds[p][2*cpi + 1]);
    *(ushort2*)(dst + ((size_t)(n*HW + p0 + p))*CC + c0 + 2*cpi) = u;
  }
}

// ---------------- MFMA sweep ----------------
// s[m][n] = sum_c gL[m][c] * gR[n][c]   (m = loop dim, n = resident dim)
// mode 0: gL=T(p), gR=I(q): colmax_q = max_m s
// mode 1: gL=T(p), gR=I(q): Wsum_q = sum_m exp(a_q + b_q s)   (params per n)
// mode 2: gL=I(q), gR=T(p): maxv_p = max_m (g_m + b_m s)      (params per m)
// grid = NB*32strips*NQ = 512 blocks, 256 threads.
__global__ __launch_bounds__(256, 2) void k_sweep_mfma(
    const ushort* __restrict__ gL, const ushort* __restrict__ gR,
    float* __restrict__ ws, const int mode)
{
  __shared__ ushort At[128][72];   // one K=64 chunk of 128 loop rows (+8 pad)
  __shared__ float red[2][128];
  __shared__ float gof[128], bof[128];

  const int t = threadIdx.x;
  const int w = t >> 6, l = t & 63;
  const int wm = w >> 1, wn = w & 1;
  const int ln31 = l & 31, lhi = l >> 5;

  const int b = blockIdx.x;
  const int h = b & 3, sid = b >> 2;
  const int n = sid >> 5;
  const int col0 = (sid & 31) * 128;
  const int loop0 = h * 1024;

  const size_t baseNC = (size_t)n * HW * CC;

  // ---- preload resident (B) fragments into registers: 16 kc x 2 in ----
  // 128 rows x 64 ushorts = 1024 chunks of 8 ushorts -> 4 iters x 256 thr.
  short8 breg[16][2];
  #pragma unroll
  for (int c2 = 0; c2 < 4; ++c2) {
    __syncthreads();
    #pragma unroll
    for (int i = 0; i < 4; ++i) {
      const int q = i*256 + t;
      const int row = q >> 3, kg = q & 7;
      *(short8*)&At[row][kg*8] =
        *(const short8*)(gR + baseNC + (size_t)(col0 + row)*CC + c2*64 + kg*8);
    }
    __syncthreads();
    #pragma unroll
    for (int kcl = 0; kcl < 4; ++kcl)
      #pragma unroll
      for (int in = 0; in < 2; ++in)
        breg[c2*4 + kcl][in] =
          *(const short8*)&At[wn*64 + in*32 + ln31][kcl*16 + lhi*8];
  }

  // per-lane mode-1 params (indexed by resident col n)
  float aq[2], bq[2];
  if (mode == 1) {
    #pragma unroll
    for (int in = 0; in < 2; ++in) {
      const int q = col0 + wn*64 + in*32 + ln31;
      aq[in] = ws[OFF_AG   + n*HW + q];
      bq[in] = ws[OFF_BETA + n*HW + q];
    }
  }

  float runv = (mode == 1) ? 0.0f : -3.0e38f;

  for (int tile = 0; tile < 8; ++tile) {
    const int tile0 = loop0 + tile*128;
    f32x16 acc[2][2];
    #pragma unroll
    for (int im = 0; im < 2; ++im)
      #pragma unroll
      for (int in = 0; in < 2; ++in)
        #pragma unroll
        for (int e = 0; e < 16; ++e) acc[im][in][e] = 0.f;

    for (int c2 = 0; c2 < 4; ++c2) {
      __syncthreads();
      #pragma unroll
      for (int i = 0; i < 4; ++i) {
        const int q = i*256 + t;
        const int row = q >> 3, kg = q & 7;
        *(short8*)&At[row][kg*8] =
          *(const short8*)(gL + baseNC + (size_t)(tile0 + row)*CC + c2*64 + kg*8);
      }
      if (mode == 2 && c2 == 0 && t < 128) {
        gof[t] = ws[OFF_AG   + n*HW + tile0 + t];
        bof[t] = ws[OFF_BETA + n*HW + tile0 + t];
      }
      __syncthreads();
      #pragma unroll
      for (int kcl = 0; kcl < 4; ++kcl) {
        const short8 a0 = *(const short8*)&At[wm*64 +  0 + ln31][kcl*16 + lhi*8];
        const short8 a1 = *(const short8*)&At[wm*64 + 32 + ln31][kcl*16 + lhi*8];
        const int kc = c2*4 + kcl;
        acc[0][0] = __builtin_amdgcn_mfma_f32_32x32x16_bf16(a0, breg[kc][0], acc[0][0], 0, 0, 0);
        acc[0][1] = __builtin_amdgcn_mfma_f32_32x32x16_bf16(a0, breg[kc][1], acc[0][1], 0, 0, 0);
        acc[1][0] = __builtin_amdgcn_mfma_f32_32x32x16_bf16(a1, breg[kc][0], acc[1][0], 0, 0, 0);
        acc[1][1] = __builtin_amdgcn_mfma_f32_32x32x16_bf16(a1, breg[kc][1], acc[1][1], 0, 0, 0);
      }
    }

    // ---- epilogue: reduce over m (rows) per n (col) ----
    // C/D layout: col = lane&31, row = (reg&3) + 8*(reg>>2) + 4*(lane>>5)
    float v[2];
    if (mode == 0) {
      #pragma unroll
      for (int in = 0; in < 2; ++in) {
        float m = -3.0e38f;
        #pragma unroll
        for (int im = 0; im < 2; ++im)
          #pragma unroll
          for (int r = 0; r < 16; ++r) m = fmaxf(m, acc[im][in][r]);
        v[in] = m;
      }
    } else if (mode == 1) {
      #pragma unroll
      for (int in = 0; in < 2; ++in) {
        float s = 0.f;
        #pragma unroll
        for (int im = 0; im < 2; ++im)
          #pragma unroll
          for (int r = 0; r < 16; ++r)
            s += __expf(fmaf(bq[in], acc[im][in][r], aq[in]));
        v[in] = s;
      }
    } else {
      #pragma unroll
      for (int in = 0; in < 2; ++in) {
        float m = -3.0e38f;
        #pragma unroll
        for (int im = 0; im < 2; ++im) {
          #pragma unroll
          for (int rg = 0; rg < 4; ++rg) {
            const int rb = wm*64 + im*32 + 4*lhi + 8*rg;
            const float4 g4 = *(const float4*)&gof[rb];
            const float4 b4 = *(const float4*)&bof[rb];
            m = fmaxf(m, fmaf(b4.x, acc[im][in][rg*4+0], g4.x));
            m = fmaxf(m, fmaf(b4.y, acc[im][in][rg*4+1], g4.y));
            m = fmaxf(m, fmaf(b4.z, acc[im][in][rg*4+2], g4.z));
            m = fmaxf(m, fmaf(b4.w, acc[im][in][rg*4+3], g4.w));
          }
        }
        v[in] = m;
      }
    }
    #pragma unroll
    for (int in = 0; in < 2; ++in) {
      const float o = __shfl_xor(v[in], 32, 64);
      v[in] = (mode == 1) ? (v[in] + o) : fmaxf(v[in], o);
    }
    if (l < 32) {
      red[wm][wn*64 +  0 + ln31] = v[0];
      red[wm][wn*64 + 32 + ln31] = v[1];
    }
    __syncthreads();
    if (t < 128) {
      if (mode == 1) runv += red[0][t] + red[1][t];
      else           runv  = fmaxf(runv, fmaxf(red[0][t], red[1][t]));
    }
    // next tile's first __syncthreads orders red reuse
  }

  if (t < 128) {
    const int base = (mode == 0) ? OFF_CMAX : ((mode == 1) ? OFF_WSUM : OFF_MAXV);
    ws[base + h*(NB*HW) + n*HW + col0 + t] = runv;
  }
}

// K4: combine colmax partials -> alpha,beta per (n,q). grid = 64
__global__ __launch_bounds__(256) void k_params(float* __restrict__ ws) {
  const int idx = blockIdx.x*256 + threadIdx.x;
  float cm = ws[OFF_CMAX + idx];
  #pragma unroll
  for (int h = 1; h < NQ; ++h) cm = fmaxf(cm, ws[OFF_CMAX + h*(NB*HW) + idx]);
  const float div   = 0.5f*(1.0f - cm);
  const float inv2d = 1.0f/(2.0f*(div + kEPS));
  ws[OFF_BETA + idx] = inv2d / kSIG;
  ws[OFF_AG   + idx] = (1.0f - inv2d) / kSIG;
}

// K6: gamma = alpha - log(Wsum + eps). grid = 64
__global__ __launch_bounds__(256) void k_gamma(float* __restrict__ ws) {
  const int idx = blockIdx.x*256 + threadIdx.x;
  float s = 0.f;
  #pragma unroll
  for (int h = 0; h < NQ; ++h) s += ws[OFF_WSUM + h*(NB*HW) + idx];
  ws[OFF_AG + idx] = ws[OFF_AG + idx] - logf(s + kEPS);
}

// K8: loss. single block.
__global__ __launch_bounds__(256) void k_final(const float* __restrict__ ws,
                                               float* __restrict__ out) {
  const int t = threadIdx.x;
  float loss = 0.f;
  for (int n = 0; n < NB; ++n) {
    float s = 0.f;
    for (int k = 0; k < 16; ++k) {
      const int idx = n*HW + k*256 + t;
      float mv = ws[OFF_MAXV + idx];
      #pragma unroll
      for (int h = 1; h < NQ; ++h) mv = fmaxf(mv, ws[OFF_MAXV + h*(NB*HW) + idx]);
      s += __expf(mv);
    }
    const float tot = blkReduceSum(s);
    loss += -logf(tot*(1.0f/4096.0f) + kEPS);
  }
  if (t == 0) out[0] = loss*0.25f;
}

extern "C" void kernel_launch(void* const* d_in, const int* in_sizes, int n_in,
                              void* d_out, int out_size, void* d_ws, size_t ws_size,
                              hipStream_t stream) {
  const float* fT = (const float*)d_in[0];
  const float* fI = (const float*)d_in[1];
  float* out = (float*)d_out;
  float* ws  = (float*)d_ws;

  const size_t need_full  = (size_t)WS_FLOATS_FULL * sizeof(float);
  const size_t need_small = (size_t)OFF_END_SMALL  * sizeof(float);

  if (ws_size >= need_full) {
    const ushort* GT = (const ushort*)(ws + OFF_GT);
    const ushort* GI = (const ushort*)(ws + OFF_GI);
    k_mean      <<<256,  256, 0, stream>>>(fT, ws);
    k_norms     <<<256,  256, 0, stream>>>(fT, fI, ws);
    k_prep      <<<2048, 256, 0, stream>>>(fT, fI, ws);
    k_sweep_mfma<<<512,  256, 0, stream>>>(GT, GI, ws, 0);  // colmax
    k_params    <<<64,   256, 0, stream>>>(ws);
    k_sweep_mfma<<<512,  256, 0, stream>>>(GT, GI, ws, 1);  // Wsum
    k_gamma     <<<64,   256, 0, stream>>>(ws);
    k_sweep_mfma<<<512,  256, 0, stream>>>(GI, GT, ws, 2);  // maxv
    k_final     <<<1,    256, 0, stream>>>(ws, out);
  } else if (ws_size >= need_small) {
    // fallback: should not trigger (ws_size measured 256 MB in R2) — but if a
    // smaller workspace ever appears, fail loudly via wrong output rather than
    // crash: run nothing. (fp32 fallback removed; it doubled compile surface.)
  }
}